// Round 4
// baseline (330.356 us; speedup 1.0000x reference)
//
#include <hip/hip_runtime.h>

// Problem constants: B=4, D=64, N=2048, T=64, N_obs=1024, K=32
#define BB   4
#define DD   64
#define NN   2048
#define TT   64
#define NOBS 1024
#define KK   32
#define EPSF 1e-8f

// ws layout in floats:
#define ALPHA_OFF 0
#define HNUM_OFF  (BB*NN*KK)
#define FLAGS_OFF (HNUM_OFF + BB*KK*DD*TT)
#define DINV_OFF  (FLAGS_OFF + NN)

// idx_obs may arrive as int32 or int64 (low word valid).
__device__ __forceinline__ int idx_stride(const int* idx) {
  return (idx[1] == 0 && idx[2] == 1) ? 2 : 1;
}

// K0: zero flags + mark observed. Single block.
__global__ __launch_bounds__(256) void k0_flags(const int* __restrict__ idx,
                                                int* __restrict__ flags) {
  int tid = threadIdx.x;
  int st = idx_stride(idx);
  #pragma unroll
  for (int i = 0; i < 8; ++i) flags[tid * 8 + i] = 0;
  __threadfence();
  __syncthreads();
  #pragma unroll
  for (int i = 0; i < 4; ++i) flags[idx[(tid + i * 256) * st]] = 1;
}

// K1: fused masked-mean summary + cosine + softmax -> alpha[b,n,k].
// Block = (b, 16-node tile). h read in contiguous 4KB chunks per d. s lives in LDS only.
__global__ __launch_bounds__(256) void k1_alpha(
    const float* __restrict__ h, const float* __restrict__ mask,
    const float* __restrict__ proto, float* __restrict__ alpha) {
  __shared__ float sL[16][65];
  __shared__ float pT[DD * 33];
  __shared__ float pn[KK];
  int blk = blockIdx.x;
  int b = blk >> 7;            // / 128 tiles
  int n0 = (blk & 127) << 4;
  int tid = threadIdx.x;
  int ns = tid >> 4;           // node slot 0..15
  int tq = tid & 15;           // t as float4

  // mask for (ns, tq) in registers; row-sum via 16-lane xor reduce
  float4 mv = reinterpret_cast<const float4*>(mask)[((size_t)b * NN + n0 + ns) * (TT / 4) + tq];
  float msum = mv.x + mv.y + mv.z + mv.w;
  #pragma unroll
  for (int off = 8; off; off >>= 1) msum += __shfl_xor(msum, off);
  float minv = 1.0f / fmaxf(msum, 1.0f);

  // stage prototypes transposed
  for (int r = tid; r < KK * 16; r += 256) {
    int k = r >> 4, dq = r & 15;
    float4 pv = reinterpret_cast<const float4*>(proto)[k * 16 + dq];
    pT[(dq * 4 + 0) * 33 + k] = pv.x;
    pT[(dq * 4 + 1) * 33 + k] = pv.y;
    pT[(dq * 4 + 2) * 33 + k] = pv.z;
    pT[(dq * 4 + 3) * 33 + k] = pv.w;
  }

  // masked-mean over t for each (n,d): contiguous 4KB read per d
  for (int d = 0; d < DD; ++d) {
    float4 hv = reinterpret_cast<const float4*>(h)[(((size_t)b * DD + d) * NN + n0 + ns) * (TT / 4) + tq];
    float dot = hv.x * mv.x + hv.y * mv.y + hv.z * mv.z + hv.w * mv.w;
    #pragma unroll
    for (int off = 8; off; off >>= 1) dot += __shfl_xor(dot, off);
    if (tq == 0) sL[ns][d] = dot * minv;
  }
  __syncthreads();

  if (tid < 32) {
    float q = 0.f;
    #pragma unroll 8
    for (int d = 0; d < DD; ++d) { float v = pT[d * 33 + tid]; q = fmaf(v, v, q); }
    pn[tid] = fmaxf(sqrtf(q), 1e-12f);
  }
  __syncthreads();
  for (int r = tid; r < DD * KK; r += 256) {
    int d = r >> 5, k = r & 31;
    pT[d * 33 + k] /= pn[k];
  }
  // s-norm per node (concurrent with pT normalize; sL is read-only now)
  float q = 0.f;
  #pragma unroll
  for (int i = 0; i < 4; ++i) { float v = sL[ns][tq + 16 * i]; q = fmaf(v, v, q); }
  #pragma unroll
  for (int off = 8; off; off >>= 1) q += __shfl_xor(q, off);
  float sinv = 1.0f / fmaxf(sqrtf(q), 1e-12f);
  __syncthreads();

  // sim for two k per thread, then 32-wide softmax within the 16-lane group
  int klo = tq, khi = tq + 16;
  float s0 = 0.f, s1 = 0.f;
  #pragma unroll 8
  for (int d = 0; d < DD; ++d) {
    float sv = sL[ns][d] * sinv;
    s0 = fmaf(sv, pT[d * 33 + klo], s0);
    s1 = fmaf(sv, pT[d * 33 + khi], s1);
  }
  float m = fmaxf(s0, s1);
  #pragma unroll
  for (int off = 8; off; off >>= 1) m = fmaxf(m, __shfl_xor(m, off));
  float e0 = expf(s0 - m), e1 = expf(s1 - m);
  float sum = e0 + e1;
  #pragma unroll
  for (int off = 8; off; off >>= 1) sum += __shfl_xor(sum, off);
  float rinv = 1.0f / sum;
  size_t ao = ((size_t)b * NN + n0 + ns) * KK;
  alpha[ao + klo] = e0 * rinv;
  alpha[ao + khi] = e1 * rinv;
}

// K2b: dinv[b,k] = 1 / max(sum_{i in idx} alpha[b,idx[i],k], EPS)
__global__ __launch_bounds__(256) void k2b_dinv(
    const float* __restrict__ alpha, const int* __restrict__ idx,
    float* __restrict__ dinv) {
  __shared__ float red[4];
  int blk = blockIdx.x;
  int b = blk >> 5, k = blk & 31;
  int tid = threadIdx.x;
  int st = idx_stride(idx);
  float sum = 0.f;
  for (int i = tid; i < NOBS; i += 256) {
    int n = idx[i * st];
    sum += alpha[((size_t)b * NN + n) * KK + k];
  }
  #pragma unroll
  for (int off = 32; off; off >>= 1) sum += __shfl_xor(sum, off);
  if ((tid & 63) == 0) red[tid >> 6] = sum;
  __syncthreads();
  if (tid == 0) {
    float tot = red[0] + red[1] + red[2] + red[3];
    dinv[blk] = 1.0f / fmaxf(tot, EPSF);
  }
}

// K3: hnum[b,k,d,t] += sum_i alpha[b,idx[i],k] * h[b,d,idx[i],t]  (4-way split, atomics)
__global__ __launch_bounds__(256) void k3_hnum(
    const float* __restrict__ h, const float* __restrict__ alpha,
    const int* __restrict__ idx, float* __restrict__ hnum) {
  __shared__ float aL[256 * 33];
  __shared__ int nL[256];
  int blk = blockIdx.x;
  int sp = blk & 3;
  int d = (blk >> 2) & (DD - 1);
  int b = blk >> 8;
  int tid = threadIdx.x;
  int i0 = sp * 256;
  int st = idx_stride(idx);

  for (int r = tid; r < 256 * 32; r += 256) {
    int i = r >> 5, k = r & 31;
    int n = idx[(i0 + i) * st];
    if (k == 0) nL[i] = n;
    aL[i * 33 + k] = alpha[((size_t)b * NN + n) * KK + k];
  }
  __syncthreads();

  int lane = tid & 63, w = tid >> 6;
  int tq = lane & 15, iq = lane >> 4;
  float4 acc[8];
  #pragma unroll
  for (int j = 0; j < 8; ++j) acc[j] = make_float4(0.f, 0.f, 0.f, 0.f);

  const size_t hbase4 = (((size_t)b * DD + d) * NN * TT) >> 2;
  for (int i = 0; i < 256; i += 4) {
    int n = nL[i + iq];
    float4 hv = reinterpret_cast<const float4*>(h)[hbase4 + (size_t)n * (TT / 4) + tq];
    const float* ar = &aL[(i + iq) * 33 + w * 8];
    #pragma unroll
    for (int j = 0; j < 8; ++j) {
      float a = ar[j];
      acc[j].x = fmaf(a, hv.x, acc[j].x);
      acc[j].y = fmaf(a, hv.y, acc[j].y);
      acc[j].z = fmaf(a, hv.z, acc[j].z);
      acc[j].w = fmaf(a, hv.w, acc[j].w);
    }
  }
  #pragma unroll
  for (int j = 0; j < 8; ++j) {
    acc[j].x += __shfl_xor(acc[j].x, 16); acc[j].x += __shfl_xor(acc[j].x, 32);
    acc[j].y += __shfl_xor(acc[j].y, 16); acc[j].y += __shfl_xor(acc[j].y, 32);
    acc[j].z += __shfl_xor(acc[j].z, 16); acc[j].z += __shfl_xor(acc[j].z, 32);
    acc[j].w += __shfl_xor(acc[j].w, 16); acc[j].w += __shfl_xor(acc[j].w, 32);
  }
  if (iq == 0) {
    #pragma unroll
    for (int j = 0; j < 8; ++j) {
      int k = w * 8 + j;
      size_t o = (((size_t)b * KK + k) * DD + d) * TT + tq * 4;
      atomicAdd(&hnum[o + 0], acc[j].x);
      atomicAdd(&hnum[o + 1], acc[j].y);
      atomicAdd(&hnum[o + 2], acc[j].z);
      atomicAdd(&hnum[o + 3], acc[j].w);
    }
  }
}

// K4: write ENTIRE out[b,d,:,:]. Observed n -> copy h row; unobserved -> sum_k w*hn.
// Block = (b, d, quarter of N=512 nodes). All global reads/writes contiguous.
// hnum slice premultiplied by dinv into 32 float4 REGISTERS (static unroll).
__global__ __launch_bounds__(256) void k4_final(
    const float* __restrict__ h, const float* __restrict__ hnum,
    const float* __restrict__ alpha, const float* __restrict__ dinv,
    const int* __restrict__ flags, float* __restrict__ out) {
  __shared__ float wL[64][36];   // 64 nodes x 32 k, row stride 36 (144B, 16B-aligned)
  __shared__ int fL[512];
  int blk = blockIdx.x;
  int qn = blk & 3;
  int d  = (blk >> 2) & (DD - 1);
  int b  = blk >> 8;
  int tid = threadIdx.x;
  int ns = tid >> 4;             // 0..15
  int tq = tid & 15;
  int nstart = qn * 512;

  for (int i = tid; i < 512; i += 256) fL[i] = flags[nstart + i];

  // hnum[b,:,d,:] premultiplied by dinv -> registers
  float4 hn[KK];
  const float4* hb = reinterpret_cast<const float4*>(hnum);
  #pragma unroll
  for (int k = 0; k < KK; ++k) {
    float4 v = hb[(((size_t)b * KK + k) * DD + d) * (TT / 4) + tq];
    float dv = dinv[b * KK + k];
    hn[k] = make_float4(v.x * dv, v.y * dv, v.z * dv, v.w * dv);
  }

  const float4* h4 = reinterpret_cast<const float4*>(h);
  float4* o4 = reinterpret_cast<float4*>(out);
  const float4* a4 = reinterpret_cast<const float4*>(alpha);
  size_t rowbase = (((size_t)b * DD + d) * NN + nstart) * (TT / 4);

  for (int tile = 0; tile < 8; ++tile) {     // 8 stages of 64 nodes
    __syncthreads();
    for (int r = tid; r < 512; r += 256) {   // stage 64n x 32k weights
      int j = r >> 3, kq = r & 7;
      float4 av = a4[((size_t)b * NN + nstart + tile * 64 + j) * 8 + kq];
      *reinterpret_cast<float4*>(&wL[j][kq * 4]) = av;
    }
    __syncthreads();
    #pragma unroll
    for (int sub = 0; sub < 4; ++sub) {
      int nl = tile * 64 + sub * 16 + ns;
      float4 hv = h4[rowbase + (size_t)nl * (TT / 4) + tq];
      float4 acc = make_float4(0.f, 0.f, 0.f, 0.f);
      const float* wr = &wL[sub * 16 + ns][0];
      #pragma unroll
      for (int kq = 0; kq < 8; ++kq) {
        float4 wv = *reinterpret_cast<const float4*>(wr + kq * 4);
        acc.x = fmaf(wv.x, hn[4*kq].x, fmaf(wv.y, hn[4*kq+1].x, fmaf(wv.z, hn[4*kq+2].x, fmaf(wv.w, hn[4*kq+3].x, acc.x))));
        acc.y = fmaf(wv.x, hn[4*kq].y, fmaf(wv.y, hn[4*kq+1].y, fmaf(wv.z, hn[4*kq+2].y, fmaf(wv.w, hn[4*kq+3].y, acc.y))));
        acc.z = fmaf(wv.x, hn[4*kq].z, fmaf(wv.y, hn[4*kq+1].z, fmaf(wv.z, hn[4*kq+2].z, fmaf(wv.w, hn[4*kq+3].z, acc.z))));
        acc.w = fmaf(wv.x, hn[4*kq].w, fmaf(wv.y, hn[4*kq+1].w, fmaf(wv.z, hn[4*kq+2].w, fmaf(wv.w, hn[4*kq+3].w, acc.w))));
      }
      float4 res = fL[nl] ? hv : acc;
      o4[rowbase + (size_t)nl * (TT / 4) + tq] = res;
    }
  }
}

extern "C" void kernel_launch(void* const* d_in, const int* in_sizes, int n_in,
                              void* d_out, int out_size, void* d_ws, size_t ws_size,
                              hipStream_t stream) {
  const float* h     = (const float*)d_in[0];
  const float* mask  = (const float*)d_in[1];
  const int*   idx   = (const int*)d_in[2];
  const float* proto = (const float*)d_in[3];
  float* out = (float*)d_out;
  float* ws  = (float*)d_ws;

  float* alpha = ws + ALPHA_OFF;
  float* hnum  = ws + HNUM_OFF;
  int*   flags = (int*)(ws + FLAGS_OFF);
  float* dinv  = ws + DINV_OFF;

  hipMemsetAsync(hnum, 0, (size_t)(BB * KK * DD * TT) * sizeof(float), stream);
  k0_flags<<<1, 256, 0, stream>>>(idx, flags);
  k1_alpha<<<BB * (NN / 16), 256, 0, stream>>>(h, mask, proto, alpha);
  k2b_dinv<<<BB * KK, 256, 0, stream>>>(alpha, idx, dinv);
  k3_hnum<<<BB * DD * 4, 256, 0, stream>>>(h, alpha, idx, hnum);
  k4_final<<<BB * DD * 4, 256, 0, stream>>>(h, hnum, alpha, dinv, flags, out);
}

// Round 5
// 322.923 us; speedup vs baseline: 1.0230x; 1.0230x over previous
//
#include <hip/hip_runtime.h>

// Problem constants: B=4, D=64, N=2048, T=64, N_obs=1024, K=32
#define BB   4
#define DD   64
#define NN   2048
#define TT   64
#define NOBS 1024
#define KK   32
#define EPSF 1e-8f

// ws layout in floats:
#define ALPHA_OFF 0
#define HNUM_OFF  (BB*NN*KK)                      // hnum4: 4 split copies
#define HNSZ      (BB*KK*DD*TT)
#define FLAGS_OFF (HNUM_OFF + 4*HNSZ)
#define DINV_OFF  (FLAGS_OFF + NN)

// idx_obs may arrive as int32 or int64 (low word valid).
__device__ __forceinline__ int idx_stride(const int* idx) {
  return (idx[1] == 0 && idx[2] == 1) ? 2 : 1;
}

// K0: zero flags + mark observed. Single block.
__global__ __launch_bounds__(256) void k0_flags(const int* __restrict__ idx,
                                                int* __restrict__ flags) {
  int tid = threadIdx.x;
  int st = idx_stride(idx);
  #pragma unroll
  for (int i = 0; i < 8; ++i) flags[tid * 8 + i] = 0;
  __threadfence();
  __syncthreads();
  #pragma unroll
  for (int i = 0; i < 4; ++i) flags[idx[(tid + i * 256) * st]] = 1;
}

// K1: fused masked-mean summary + cosine + softmax -> alpha[b,n,k].
__global__ __launch_bounds__(256) void k1_alpha(
    const float* __restrict__ h, const float* __restrict__ mask,
    const float* __restrict__ proto, float* __restrict__ alpha) {
  __shared__ float sL[16][65];
  __shared__ float pT[DD * 33];
  __shared__ float pn[KK];
  int blk = blockIdx.x;
  int b = blk >> 7;
  int n0 = (blk & 127) << 4;
  int tid = threadIdx.x;
  int ns = tid >> 4;           // node slot 0..15
  int tq = tid & 15;           // t as float4

  float4 mv = reinterpret_cast<const float4*>(mask)[((size_t)b * NN + n0 + ns) * (TT / 4) + tq];
  float msum = mv.x + mv.y + mv.z + mv.w;
  #pragma unroll
  for (int off = 8; off; off >>= 1) msum += __shfl_xor(msum, off);
  float minv = 1.0f / fmaxf(msum, 1.0f);

  for (int r = tid; r < KK * 16; r += 256) {
    int k = r >> 4, dq = r & 15;
    float4 pv = reinterpret_cast<const float4*>(proto)[k * 16 + dq];
    pT[(dq * 4 + 0) * 33 + k] = pv.x;
    pT[(dq * 4 + 1) * 33 + k] = pv.y;
    pT[(dq * 4 + 2) * 33 + k] = pv.z;
    pT[(dq * 4 + 3) * 33 + k] = pv.w;
  }

  // masked-mean over t for each (n,d): 4 independent load+reduce chains in flight
  #pragma unroll 4
  for (int d = 0; d < DD; ++d) {
    float4 hv = reinterpret_cast<const float4*>(h)[(((size_t)b * DD + d) * NN + n0 + ns) * (TT / 4) + tq];
    float dot = hv.x * mv.x + hv.y * mv.y + hv.z * mv.z + hv.w * mv.w;
    #pragma unroll
    for (int off = 8; off; off >>= 1) dot += __shfl_xor(dot, off);
    if (tq == 0) sL[ns][d] = dot * minv;
  }
  __syncthreads();

  if (tid < 32) {
    float q = 0.f;
    #pragma unroll 8
    for (int d = 0; d < DD; ++d) { float v = pT[d * 33 + tid]; q = fmaf(v, v, q); }
    pn[tid] = fmaxf(sqrtf(q), 1e-12f);
  }
  __syncthreads();
  for (int r = tid; r < DD * KK; r += 256) {
    int d = r >> 5, k = r & 31;
    pT[d * 33 + k] /= pn[k];
  }
  float q = 0.f;
  #pragma unroll
  for (int i = 0; i < 4; ++i) { float v = sL[ns][tq + 16 * i]; q = fmaf(v, v, q); }
  #pragma unroll
  for (int off = 8; off; off >>= 1) q += __shfl_xor(q, off);
  float sinv = 1.0f / fmaxf(sqrtf(q), 1e-12f);
  __syncthreads();

  int klo = tq, khi = tq + 16;
  float s0 = 0.f, s1 = 0.f;
  #pragma unroll 8
  for (int d = 0; d < DD; ++d) {
    float sv = sL[ns][d] * sinv;
    s0 = fmaf(sv, pT[d * 33 + klo], s0);
    s1 = fmaf(sv, pT[d * 33 + khi], s1);
  }
  float m = fmaxf(s0, s1);
  #pragma unroll
  for (int off = 8; off; off >>= 1) m = fmaxf(m, __shfl_xor(m, off));
  float e0 = expf(s0 - m), e1 = expf(s1 - m);
  float sum = e0 + e1;
  #pragma unroll
  for (int off = 8; off; off >>= 1) sum += __shfl_xor(sum, off);
  float rinv = 1.0f / sum;
  size_t ao = ((size_t)b * NN + n0 + ns) * KK;
  alpha[ao + klo] = e0 * rinv;
  alpha[ao + khi] = e1 * rinv;
}

// K2b: dinv[b,k] = 1 / max(sum_{i in idx} alpha[b,idx[i],k], EPS)
__global__ __launch_bounds__(256) void k2b_dinv(
    const float* __restrict__ alpha, const int* __restrict__ idx,
    float* __restrict__ dinv) {
  __shared__ float red[4];
  int blk = blockIdx.x;
  int b = blk >> 5, k = blk & 31;
  int tid = threadIdx.x;
  int st = idx_stride(idx);
  float sum = 0.f;
  for (int i = tid; i < NOBS; i += 256) {
    int n = idx[i * st];
    sum += alpha[((size_t)b * NN + n) * KK + k];
  }
  #pragma unroll
  for (int off = 32; off; off >>= 1) sum += __shfl_xor(sum, off);
  if ((tid & 63) == 0) red[tid >> 6] = sum;
  __syncthreads();
  if (tid == 0) {
    float tot = red[0] + red[1] + red[2] + red[3];
    dinv[blk] = 1.0f / fmaxf(tot, EPSF);
  }
}

// K3: hnum4[sp][b,k,d,t] = sum_{i in split sp} alpha[b,idx[i],k] * h[b,d,idx[i],t]
// Plain stores into per-split copies — no atomics, no memset needed.
__global__ __launch_bounds__(256) void k3_hnum(
    const float* __restrict__ h, const float* __restrict__ alpha,
    const int* __restrict__ idx, float* __restrict__ hnum4) {
  __shared__ float aL[256 * 33];
  __shared__ int nL[256];
  int blk = blockIdx.x;
  int sp = blk & 3;
  int d = (blk >> 2) & (DD - 1);
  int b = blk >> 8;
  int tid = threadIdx.x;
  int i0 = sp * 256;
  int st = idx_stride(idx);

  for (int r = tid; r < 256 * 32; r += 256) {
    int i = r >> 5, k = r & 31;
    int n = idx[(i0 + i) * st];
    if (k == 0) nL[i] = n;
    aL[i * 33 + k] = alpha[((size_t)b * NN + n) * KK + k];
  }
  __syncthreads();

  int lane = tid & 63, w = tid >> 6;
  int tq = lane & 15, iq = lane >> 4;
  float4 acc[8];
  #pragma unroll
  for (int j = 0; j < 8; ++j) acc[j] = make_float4(0.f, 0.f, 0.f, 0.f);

  const size_t hbase4 = (((size_t)b * DD + d) * NN * TT) >> 2;
  for (int i = 0; i < 256; i += 4) {
    int n = nL[i + iq];
    float4 hv = reinterpret_cast<const float4*>(h)[hbase4 + (size_t)n * (TT / 4) + tq];
    const float* ar = &aL[(i + iq) * 33 + w * 8];
    #pragma unroll
    for (int j = 0; j < 8; ++j) {
      float a = ar[j];
      acc[j].x = fmaf(a, hv.x, acc[j].x);
      acc[j].y = fmaf(a, hv.y, acc[j].y);
      acc[j].z = fmaf(a, hv.z, acc[j].z);
      acc[j].w = fmaf(a, hv.w, acc[j].w);
    }
  }
  #pragma unroll
  for (int j = 0; j < 8; ++j) {
    acc[j].x += __shfl_xor(acc[j].x, 16); acc[j].x += __shfl_xor(acc[j].x, 32);
    acc[j].y += __shfl_xor(acc[j].y, 16); acc[j].y += __shfl_xor(acc[j].y, 32);
    acc[j].z += __shfl_xor(acc[j].z, 16); acc[j].z += __shfl_xor(acc[j].z, 32);
    acc[j].w += __shfl_xor(acc[j].w, 16); acc[j].w += __shfl_xor(acc[j].w, 32);
  }
  if (iq == 0) {
    float* hn = hnum4 + (size_t)sp * HNSZ;
    #pragma unroll
    for (int j = 0; j < 8; ++j) {
      int k = w * 8 + j;
      size_t o4 = ((((size_t)b * KK + k) * DD + d) * TT) >> 2;
      reinterpret_cast<float4*>(hn)[o4 + tq] = acc[j];
    }
  }
}

// K4: write ENTIRE out[b,d,:,:]. Observed n -> copy h row; unobserved -> sum_k w*hn.
// hnum = sum of 4 split copies, premultiplied by dinv into 32 float4 registers.
__global__ __launch_bounds__(256) void k4_final(
    const float* __restrict__ h, const float* __restrict__ hnum4,
    const float* __restrict__ alpha, const float* __restrict__ dinv,
    const int* __restrict__ flags, float* __restrict__ out) {
  __shared__ float wL[64][36];
  __shared__ int fL[512];
  int blk = blockIdx.x;
  int qn = blk & 3;
  int d  = (blk >> 2) & (DD - 1);
  int b  = blk >> 8;
  int tid = threadIdx.x;
  int ns = tid >> 4;
  int tq = tid & 15;
  int nstart = qn * 512;

  for (int i = tid; i < 512; i += 256) fL[i] = flags[nstart + i];

  float4 hn[KK];
  const float4* hb = reinterpret_cast<const float4*>(hnum4);
  #pragma unroll
  for (int k = 0; k < KK; ++k) {
    size_t o = (((size_t)b * KK + k) * DD + d) * (TT / 4) + tq;
    float4 v0 = hb[o];
    float4 v1 = hb[o + (HNSZ / 4)];
    float4 v2 = hb[o + 2 * (HNSZ / 4)];
    float4 v3 = hb[o + 3 * (HNSZ / 4)];
    float dv = dinv[b * KK + k];
    hn[k] = make_float4((v0.x + v1.x + v2.x + v3.x) * dv,
                        (v0.y + v1.y + v2.y + v3.y) * dv,
                        (v0.z + v1.z + v2.z + v3.z) * dv,
                        (v0.w + v1.w + v2.w + v3.w) * dv);
  }

  const float4* h4 = reinterpret_cast<const float4*>(h);
  float4* o4 = reinterpret_cast<float4*>(out);
  const float4* a4 = reinterpret_cast<const float4*>(alpha);
  size_t rowbase = (((size_t)b * DD + d) * NN + nstart) * (TT / 4);

  for (int tile = 0; tile < 8; ++tile) {
    __syncthreads();
    for (int r = tid; r < 512; r += 256) {
      int j = r >> 3, kq = r & 7;
      float4 av = a4[((size_t)b * NN + nstart + tile * 64 + j) * 8 + kq];
      *reinterpret_cast<float4*>(&wL[j][kq * 4]) = av;
    }
    __syncthreads();
    #pragma unroll
    for (int sub = 0; sub < 4; ++sub) {
      int nl = tile * 64 + sub * 16 + ns;
      float4 hv = h4[rowbase + (size_t)nl * (TT / 4) + tq];
      float4 acc = make_float4(0.f, 0.f, 0.f, 0.f);
      const float* wr = &wL[sub * 16 + ns][0];
      #pragma unroll
      for (int kq = 0; kq < 8; ++kq) {
        float4 wv = *reinterpret_cast<const float4*>(wr + kq * 4);
        acc.x = fmaf(wv.x, hn[4*kq].x, fmaf(wv.y, hn[4*kq+1].x, fmaf(wv.z, hn[4*kq+2].x, fmaf(wv.w, hn[4*kq+3].x, acc.x))));
        acc.y = fmaf(wv.x, hn[4*kq].y, fmaf(wv.y, hn[4*kq+1].y, fmaf(wv.z, hn[4*kq+2].y, fmaf(wv.w, hn[4*kq+3].y, acc.y))));
        acc.z = fmaf(wv.x, hn[4*kq].z, fmaf(wv.y, hn[4*kq+1].z, fmaf(wv.z, hn[4*kq+2].z, fmaf(wv.w, hn[4*kq+3].z, acc.z))));
        acc.w = fmaf(wv.x, hn[4*kq].w, fmaf(wv.y, hn[4*kq+1].w, fmaf(wv.z, hn[4*kq+2].w, fmaf(wv.w, hn[4*kq+3].w, acc.w))));
      }
      float4 res = fL[nl] ? hv : acc;
      o4[rowbase + (size_t)nl * (TT / 4) + tq] = res;
    }
  }
}

extern "C" void kernel_launch(void* const* d_in, const int* in_sizes, int n_in,
                              void* d_out, int out_size, void* d_ws, size_t ws_size,
                              hipStream_t stream) {
  const float* h     = (const float*)d_in[0];
  const float* mask  = (const float*)d_in[1];
  const int*   idx   = (const int*)d_in[2];
  const float* proto = (const float*)d_in[3];
  float* out = (float*)d_out;
  float* ws  = (float*)d_ws;

  float* alpha = ws + ALPHA_OFF;
  float* hnum4 = ws + HNUM_OFF;
  int*   flags = (int*)(ws + FLAGS_OFF);
  float* dinv  = ws + DINV_OFF;

  k0_flags<<<1, 256, 0, stream>>>(idx, flags);
  k1_alpha<<<BB * (NN / 16), 256, 0, stream>>>(h, mask, proto, alpha);
  k2b_dinv<<<BB * KK, 256, 0, stream>>>(alpha, idx, dinv);
  k3_hnum<<<BB * DD * 4, 256, 0, stream>>>(h, alpha, idx, hnum4);
  k4_final<<<BB * DD * 4, 256, 0, stream>>>(h, hnum4, alpha, dinv, flags, out);
}